// Round 2
// baseline (4475.912 us; speedup 1.0000x reference)
//
#include <hip/hip_runtime.h>
#include <hip/hip_bf16.h>
#include <cmath>

// Problem: TransformerBlock  B=4 T=2048 C=512 H=8 D=64  (f32 I/O, bf16/f32 internal)

using u16 = unsigned short;

constexpr int B_ = 4, T_ = 2048, C_ = 512, H_ = 8, D_ = 64;
constexpr int BT = B_ * T_;                // 8192 rows
constexpr int KQV_SEC = B_ * H_ * T_ * D_; // 4194304 elems per k/q/v section

__device__ __forceinline__ float b2f(u16 u) {
    return __uint_as_float(((unsigned)u) << 16);
}
__device__ __forceinline__ u16 f2b(float f) {
    __hip_bfloat16 h = __float2bfloat16(f);
    return *reinterpret_cast<u16*>(&h);
}

// ---------------- LayerNorm stats: mean + rstd per row (C=512) ----------------
__global__ __launch_bounds__(256) void ln_stats_k(const float* __restrict__ x,
                                                  float* __restrict__ stats) {
    const int r = blockIdx.x;
    const int t = threadIdx.x;
    float v0 = x[(size_t)r * C_ + t];
    float v1 = x[(size_t)r * C_ + t + 256];
    __shared__ float rs[256], rq[256];
    rs[t] = v0 + v1;
    rq[t] = v0 * v0 + v1 * v1;
    __syncthreads();
    for (int k = 128; k; k >>= 1) {
        if (t < k) { rs[t] += rs[t + k]; rq[t] += rq[t + k]; }
        __syncthreads();
    }
    if (t == 0) {
        float m = rs[0] * (1.0f / C_);
        float var = rq[0] * (1.0f / C_) - m * m;
        stats[2 * r] = m;
        stats[2 * r + 1] = rsqrtf(var + 1e-5f);
    }
}

// ---------------- Generic 64x64 tiled GEMM: out = A @ W^T (+bias) ----------------
// A, W, bias are f32. AMODE: 0 = plain A, 1 = LayerNorm(stats) applied to A rows.
// EPI:   0 = kqv scatter (+bias, out bf16 k/q/v sections)
//        1 = proj residual (+bias, resid f32 x, out f32 x2)
//        2 = fc gelu (+bias, out bf16 h)
//        3 = cproj residual (no bias, resid f32 x2, out f32 d_out)
template <int AMODE, int EPI>
__global__ __launch_bounds__(256) void gemm64(const float* __restrict__ A,
                                              const float* __restrict__ W,
                                              const float* __restrict__ bias,
                                              const float* __restrict__ stats,
                                              const float* __restrict__ resid,
                                              void* __restrict__ out, int K) {
    __shared__ float As[32][68];
    __shared__ float Bs[32][68];
    const int tid = threadIdx.x;
    const int tx = tid & 15, ty = tid >> 4;
    const int n0 = blockIdx.x * 64, r0 = blockIdx.y * 64;
    const int N = gridDim.x * 64;

    float acc[4][4] = {};

    for (int kk = 0; kk < K; kk += 32) {
#pragma unroll
        for (int it = 0; it < 2; ++it) {
            const int e = (it * 256 + tid) * 4;
            const int row = e >> 5, col = e & 31;
            // stage A (with optional on-the-fly LayerNorm)
            float4 u = *(const float4*)(A + (size_t)(r0 + row) * K + kk + col);
            float f[4] = {u.x, u.y, u.z, u.w};
            if constexpr (AMODE == 1) {
                float m = stats[2 * (r0 + row)];
                float rstd = stats[2 * (r0 + row) + 1];
#pragma unroll
                for (int i = 0; i < 4; ++i) f[i] = (f[i] - m) * rstd;
            }
#pragma unroll
            for (int i = 0; i < 4; ++i) As[col + i][row] = f[i];
            // stage B (weights, row-major [N][K])
            float4 w = *(const float4*)(W + (size_t)(n0 + row) * K + kk + col);
            Bs[col + 0][row] = w.x;
            Bs[col + 1][row] = w.y;
            Bs[col + 2][row] = w.z;
            Bs[col + 3][row] = w.w;
        }
        __syncthreads();
#pragma unroll
        for (int k = 0; k < 32; ++k) {
            float4 a = *(const float4*)&As[k][ty * 4];
            float4 b = *(const float4*)&Bs[k][tx * 4];
            acc[0][0] += a.x * b.x; acc[0][1] += a.x * b.y; acc[0][2] += a.x * b.z; acc[0][3] += a.x * b.w;
            acc[1][0] += a.y * b.x; acc[1][1] += a.y * b.y; acc[1][2] += a.y * b.z; acc[1][3] += a.y * b.w;
            acc[2][0] += a.z * b.x; acc[2][1] += a.z * b.y; acc[2][2] += a.z * b.z; acc[2][3] += a.z * b.w;
            acc[3][0] += a.w * b.x; acc[3][1] += a.w * b.y; acc[3][2] += a.w * b.z; acc[3][3] += a.w * b.w;
        }
        __syncthreads();
    }

#pragma unroll
    for (int i = 0; i < 4; ++i) {
        const int r = r0 + ty * 4 + i;
#pragma unroll
        for (int j = 0; j < 4; ++j) {
            const int n = n0 + tx * 4 + j;
            float v = acc[i][j];
            if constexpr (EPI != 3) v += bias[n];
            if constexpr (EPI == 0) {
                const int s = n >> 9, rem = n & 511;
                const int h = rem >> 6, dd = rem & 63;
                const int b = r >> 11, t = r & 2047;
                ((u16*)out)[(size_t)s * KQV_SEC +
                            (((size_t)(b * H_ + h) * T_ + t) * D_ + dd)] = f2b(v);
            } else if constexpr (EPI == 1) {
                v += resid[(size_t)r * N + n];
                ((float*)out)[(size_t)r * N + n] = v;
            } else if constexpr (EPI == 2) {
                float g = 0.5f * v * (1.0f + erff(v * 0.70710678118654752f));
                ((u16*)out)[(size_t)r * N + n] = f2b(g);
            } else {
                v += resid[(size_t)r * N + n];
                ((float*)out)[(size_t)r * N + n] = v;
            }
        }
    }
}

// A-operand as bf16 (internal buffers), rest f32
template <int EPI>
__global__ __launch_bounds__(256) void gemm64b(const u16* __restrict__ A,
                                               const float* __restrict__ W,
                                               const float* __restrict__ bias,
                                               const float* __restrict__ resid,
                                               void* __restrict__ out, int K) {
    __shared__ float As[32][68];
    __shared__ float Bs[32][68];
    const int tid = threadIdx.x;
    const int tx = tid & 15, ty = tid >> 4;
    const int n0 = blockIdx.x * 64, r0 = blockIdx.y * 64;
    const int N = gridDim.x * 64;

    float acc[4][4] = {};

    for (int kk = 0; kk < K; kk += 32) {
#pragma unroll
        for (int it = 0; it < 2; ++it) {
            const int e = (it * 256 + tid) * 4;
            const int row = e >> 5, col = e & 31;
            ushort4 u = *(const ushort4*)(A + (size_t)(r0 + row) * K + kk + col);
            As[col + 0][row] = b2f(u.x);
            As[col + 1][row] = b2f(u.y);
            As[col + 2][row] = b2f(u.z);
            As[col + 3][row] = b2f(u.w);
            float4 w = *(const float4*)(W + (size_t)(n0 + row) * K + kk + col);
            Bs[col + 0][row] = w.x;
            Bs[col + 1][row] = w.y;
            Bs[col + 2][row] = w.z;
            Bs[col + 3][row] = w.w;
        }
        __syncthreads();
#pragma unroll
        for (int k = 0; k < 32; ++k) {
            float4 a = *(const float4*)&As[k][ty * 4];
            float4 b = *(const float4*)&Bs[k][tx * 4];
            acc[0][0] += a.x * b.x; acc[0][1] += a.x * b.y; acc[0][2] += a.x * b.z; acc[0][3] += a.x * b.w;
            acc[1][0] += a.y * b.x; acc[1][1] += a.y * b.y; acc[1][2] += a.y * b.z; acc[1][3] += a.y * b.w;
            acc[2][0] += a.z * b.x; acc[2][1] += a.z * b.y; acc[2][2] += a.z * b.z; acc[2][3] += a.z * b.w;
            acc[3][0] += a.w * b.x; acc[3][1] += a.w * b.y; acc[3][2] += a.w * b.z; acc[3][3] += a.w * b.w;
        }
        __syncthreads();
    }

#pragma unroll
    for (int i = 0; i < 4; ++i) {
        const int r = r0 + ty * 4 + i;
#pragma unroll
        for (int j = 0; j < 4; ++j) {
            const int n = n0 + tx * 4 + j;
            float v = acc[i][j];
            if constexpr (EPI != 3) v += bias[n];
            if constexpr (EPI == 1) {
                v += resid[(size_t)r * N + n];
                ((float*)out)[(size_t)r * N + n] = v;
            } else {
                v += resid[(size_t)r * N + n];
                ((float*)out)[(size_t)r * N + n] = v;
            }
        }
    }
}

// ---------------- Attention: one block = 8 query rows of one (b,h) ----------------
__global__ __launch_bounds__(256) void attn_k(const u16* __restrict__ Kb,
                                              const u16* __restrict__ Qb,
                                              const u16* __restrict__ Vb,
                                              u16* __restrict__ agg) {
    __shared__ float q_s[8][64];
    __shared__ float sc[8][2048];   // 64 KB
    __shared__ float red[256];
    __shared__ float inv_s[8];

    const int t = threadIdx.x;
    const int bh = blockIdx.x >> 8;   // 0..31
    const int qt = blockIdx.x & 255;  // 0..255 (q-tile of 8 rows)
    const int b = bh >> 3, h = bh & 7;

    // load 8 q rows, pre-scaled by 1/sqrt(d)
    {
        const int e = t * 2;
        const int qi = e >> 6, d = e & 63;
        const u16* qp = Qb + ((size_t)bh * T_ + qt * 8 + qi) * D_ + d;
        q_s[qi][d] = b2f(qp[0]) * 0.125f;
        q_s[qi][d + 1] = b2f(qp[1]) * 0.125f;
    }
    __syncthreads();

    // scores: each thread handles 8 key rows x all 8 q rows
    for (int i = 0; i < 8; ++i) {
        const int j = i * 256 + t;
        const ushort4* kp = (const ushort4*)(Kb + ((size_t)bh * T_ + j) * D_);
        float4 kr[16];
#pragma unroll
        for (int c = 0; c < 16; ++c) {
            ushort4 u = kp[c];
            kr[c] = make_float4(b2f(u.x), b2f(u.y), b2f(u.z), b2f(u.w));
        }
#pragma unroll
        for (int qi = 0; qi < 8; ++qi) {
            const float4* q4 = (const float4*)q_s[qi];
            float s = 0.f;
#pragma unroll
            for (int c = 0; c < 16; ++c) {
                float4 qv = q4[c];
                s += kr[c].x * qv.x + kr[c].y * qv.y + kr[c].z * qv.z + kr[c].w * qv.w;
            }
            sc[qi][j] = s;
        }
    }
    __syncthreads();

    // softmax per row (leave unnormalized exp in sc, keep 1/sum)
    for (int qi = 0; qi < 8; ++qi) {
        float lm = -3.4e38f;
#pragma unroll
        for (int i = 0; i < 8; ++i) lm = fmaxf(lm, sc[qi][i * 256 + t]);
        red[t] = lm;
        __syncthreads();
        for (int k = 128; k; k >>= 1) {
            if (t < k) red[t] = fmaxf(red[t], red[t + k]);
            __syncthreads();
        }
        const float mx = red[0];
        __syncthreads();
        float ls = 0.f;
#pragma unroll
        for (int i = 0; i < 8; ++i) {
            float p = __expf(sc[qi][i * 256 + t] - mx);
            sc[qi][i * 256 + t] = p;
            ls += p;
        }
        red[t] = ls;
        __syncthreads();
        for (int k = 128; k; k >>= 1) {
            if (t < k) red[t] += red[t + k];
            __syncthreads();
        }
        if (t == 0) inv_s[qi] = 1.0f / red[0];
        __syncthreads();
    }

    // PV: thread -> (qi = t>>5, d2 = (t&31)*2); wave reads one V row coalesced
    {
        const int g = t >> 5;           // 0..7 (q row)
        const int d2 = (t & 31) * 2;    // 0..62
        float a0 = 0.f, a1 = 0.f;
        const u16* vp = Vb + (size_t)bh * T_ * D_ + d2;
        for (int j = 0; j < T_; ++j) {
            ushort2 v = *(const ushort2*)(vp + (size_t)j * D_);
            float p = sc[g][j];
            a0 += p * b2f(v.x);
            a1 += p * b2f(v.y);
        }
        const float inv = inv_s[g];
        const int tq = qt * 8 + g;
        u16* op = agg + ((size_t)(b * T_ + tq)) * C_ + h * D_ + d2;
        ushort2 o;
        o.x = f2b(a0 * inv);
        o.y = f2b(a1 * inv);
        *(ushort2*)op = o;
    }
}

// ---------------- launch ----------------
extern "C" void kernel_launch(void* const* d_in, const int* in_sizes, int n_in,
                              void* d_out, int out_size, void* d_ws, size_t ws_size,
                              hipStream_t stream) {
    (void)in_sizes; (void)n_in; (void)out_size; (void)ws_size;
    const float* x       = (const float*)d_in[0];
    const float* w_kqv   = (const float*)d_in[1];
    const float* b_kqv   = (const float*)d_in[2];
    const float* w_proj  = (const float*)d_in[3];
    const float* b_proj  = (const float*)d_in[4];
    const float* w_fc    = (const float*)d_in[5];
    const float* b_fc    = (const float*)d_in[6];
    const float* w_cproj = (const float*)d_in[7];

    char* ws = (char*)d_ws;
    float* stats = (float*)ws;                                   // 64 KB
    u16* kqv = (u16*)(ws + 65536);                               // 3 * 8 MB
    u16* agg = (u16*)(ws + 65536 + 3ull * KQV_SEC * 2);          // 8 MB
    float* x2 = (float*)(ws + 65536 + 3ull * KQV_SEC * 2 + (size_t)BT * C_ * 2); // 16 MB
    u16* hbuf = (u16*)((char*)x2 + (size_t)BT * C_ * 4);         // 16 MB

    // 1) ln1 stats on x
    ln_stats_k<<<BT, 256, 0, stream>>>(x, stats);
    // 2) kqv = ln(x) @ w_kqv^T + b_kqv, scattered to k/q/v [B*H][T][64] (bf16)
    gemm64<1, 0><<<dim3(1536 / 64, BT / 64), 256, 0, stream>>>(
        x, w_kqv, b_kqv, stats, nullptr, kqv, 512);
    // 3) attention -> agg (B,T,C) bf16
    attn_k<<<B_ * H_ * (T_ / 8), 256, 0, stream>>>(
        kqv, kqv + KQV_SEC, kqv + 2 * KQV_SEC, agg);
    // 4) x2 = x + agg @ w_proj^T + b_proj   (f32)
    gemm64b<1><<<dim3(512 / 64, BT / 64), 256, 0, stream>>>(
        agg, w_proj, b_proj, x, x2, 512);
    // 5) ln2 stats on x2
    ln_stats_k<<<BT, 256, 0, stream>>>(x2, stats);
    // 6) h = gelu(ln(x2) @ w_fc^T + b_fc)   (bf16)
    gemm64<1, 2><<<dim3(1024 / 64, BT / 64), 256, 0, stream>>>(
        x2, w_fc, b_fc, stats, nullptr, hbuf, 512);
    // 7) out = x2 + h @ w_cproj^T           (f32)
    gemm64b<3><<<dim3(512 / 64, BT / 64), 256, 0, stream>>>(
        hbuf, w_cproj, nullptr, x2, d_out, 1024);
}

// Round 3
// 667.162 us; speedup vs baseline: 6.7089x; 6.7089x over previous
//
#include <hip/hip_runtime.h>
#include <hip/hip_bf16.h>
#include <cmath>

// Problem: TransformerBlock  B=4 T=2048 C=512 H=8 D=64  (f32 I/O, bf16/f32 internal)

using u16 = unsigned short;
typedef __attribute__((ext_vector_type(4))) float f32x4;
typedef __attribute__((ext_vector_type(8))) short bf16x8;

constexpr int B_ = 4, T_ = 2048, C_ = 512, H_ = 8, D_ = 64;
constexpr int BT = B_ * T_;                // 8192 rows
constexpr int KQV_SEC = B_ * H_ * T_ * D_; // 4194304 elems per k/q/v section

__device__ __forceinline__ float b2f(u16 u) {
    return __uint_as_float(((unsigned)u) << 16);
}
__device__ __forceinline__ u16 f2b(float f) {
    __hip_bfloat16 h = __float2bfloat16(f);
    return *reinterpret_cast<u16*>(&h);
}

// ---------------- LayerNorm stats: mean + rstd per row (C=512) ----------------
__global__ __launch_bounds__(256) void ln_stats_k(const float* __restrict__ x,
                                                  float* __restrict__ stats) {
    const int r = blockIdx.x;
    const int t = threadIdx.x;
    float v0 = x[(size_t)r * C_ + t];
    float v1 = x[(size_t)r * C_ + t + 256];
    __shared__ float rs[256], rq[256];
    rs[t] = v0 + v1;
    rq[t] = v0 * v0 + v1 * v1;
    __syncthreads();
    for (int k = 128; k; k >>= 1) {
        if (t < k) { rs[t] += rs[t + k]; rq[t] += rq[t + k]; }
        __syncthreads();
    }
    if (t == 0) {
        float m = rs[0] * (1.0f / C_);
        float var = rq[0] * (1.0f / C_) - m * m;
        stats[2 * r] = m;
        stats[2 * r + 1] = rsqrtf(var + 1e-5f);
    }
}

// ---------------- Generic 64x64 tiled GEMM: out = A @ W^T (+bias) ----------------
template <int AMODE, int EPI>
__global__ __launch_bounds__(256) void gemm64(const float* __restrict__ A,
                                              const float* __restrict__ W,
                                              const float* __restrict__ bias,
                                              const float* __restrict__ stats,
                                              const float* __restrict__ resid,
                                              void* __restrict__ out, int K) {
    __shared__ float As[32][68];
    __shared__ float Bs[32][68];
    const int tid = threadIdx.x;
    const int tx = tid & 15, ty = tid >> 4;
    const int n0 = blockIdx.x * 64, r0 = blockIdx.y * 64;
    const int N = gridDim.x * 64;

    float acc[4][4] = {};

    for (int kk = 0; kk < K; kk += 32) {
#pragma unroll
        for (int it = 0; it < 2; ++it) {
            const int e = (it * 256 + tid) * 4;
            const int row = e >> 5, col = e & 31;
            float4 u = *(const float4*)(A + (size_t)(r0 + row) * K + kk + col);
            float f[4] = {u.x, u.y, u.z, u.w};
            if constexpr (AMODE == 1) {
                float m = stats[2 * (r0 + row)];
                float rstd = stats[2 * (r0 + row) + 1];
#pragma unroll
                for (int i = 0; i < 4; ++i) f[i] = (f[i] - m) * rstd;
            }
#pragma unroll
            for (int i = 0; i < 4; ++i) As[col + i][row] = f[i];
            float4 w = *(const float4*)(W + (size_t)(n0 + row) * K + kk + col);
            Bs[col + 0][row] = w.x;
            Bs[col + 1][row] = w.y;
            Bs[col + 2][row] = w.z;
            Bs[col + 3][row] = w.w;
        }
        __syncthreads();
#pragma unroll
        for (int k = 0; k < 32; ++k) {
            float4 a = *(const float4*)&As[k][ty * 4];
            float4 b = *(const float4*)&Bs[k][tx * 4];
            acc[0][0] += a.x * b.x; acc[0][1] += a.x * b.y; acc[0][2] += a.x * b.z; acc[0][3] += a.x * b.w;
            acc[1][0] += a.y * b.x; acc[1][1] += a.y * b.y; acc[1][2] += a.y * b.z; acc[1][3] += a.y * b.w;
            acc[2][0] += a.z * b.x; acc[2][1] += a.z * b.y; acc[2][2] += a.z * b.z; acc[2][3] += a.z * b.w;
            acc[3][0] += a.w * b.x; acc[3][1] += a.w * b.y; acc[3][2] += a.w * b.z; acc[3][3] += a.w * b.w;
        }
        __syncthreads();
    }

#pragma unroll
    for (int i = 0; i < 4; ++i) {
        const int r = r0 + ty * 4 + i;
#pragma unroll
        for (int j = 0; j < 4; ++j) {
            const int n = n0 + tx * 4 + j;
            float v = acc[i][j];
            if constexpr (EPI != 3) v += bias[n];
            if constexpr (EPI == 0) {
                const int s = n >> 9, rem = n & 511;
                const int h = rem >> 6, dd = rem & 63;
                const int b = r >> 11, t = r & 2047;
                ((u16*)out)[(size_t)s * KQV_SEC +
                            (((size_t)(b * H_ + h) * T_ + t) * D_ + dd)] = f2b(v);
            } else if constexpr (EPI == 1) {
                v += resid[(size_t)r * N + n];
                ((float*)out)[(size_t)r * N + n] = v;
            } else if constexpr (EPI == 2) {
                float g = 0.5f * v * (1.0f + erff(v * 0.70710678118654752f));
                ((u16*)out)[(size_t)r * N + n] = f2b(g);
            } else {
                v += resid[(size_t)r * N + n];
                ((float*)out)[(size_t)r * N + n] = v;
            }
        }
    }
}

// A-operand as bf16 (internal buffers), rest f32
template <int EPI>
__global__ __launch_bounds__(256) void gemm64b(const u16* __restrict__ A,
                                               const float* __restrict__ W,
                                               const float* __restrict__ bias,
                                               const float* __restrict__ resid,
                                               void* __restrict__ out, int K) {
    __shared__ float As[32][68];
    __shared__ float Bs[32][68];
    const int tid = threadIdx.x;
    const int tx = tid & 15, ty = tid >> 4;
    const int n0 = blockIdx.x * 64, r0 = blockIdx.y * 64;
    const int N = gridDim.x * 64;

    float acc[4][4] = {};

    for (int kk = 0; kk < K; kk += 32) {
#pragma unroll
        for (int it = 0; it < 2; ++it) {
            const int e = (it * 256 + tid) * 4;
            const int row = e >> 5, col = e & 31;
            ushort4 u = *(const ushort4*)(A + (size_t)(r0 + row) * K + kk + col);
            As[col + 0][row] = b2f(u.x);
            As[col + 1][row] = b2f(u.y);
            As[col + 2][row] = b2f(u.z);
            As[col + 3][row] = b2f(u.w);
            float4 w = *(const float4*)(W + (size_t)(n0 + row) * K + kk + col);
            Bs[col + 0][row] = w.x;
            Bs[col + 1][row] = w.y;
            Bs[col + 2][row] = w.z;
            Bs[col + 3][row] = w.w;
        }
        __syncthreads();
#pragma unroll
        for (int k = 0; k < 32; ++k) {
            float4 a = *(const float4*)&As[k][ty * 4];
            float4 b = *(const float4*)&Bs[k][tx * 4];
            acc[0][0] += a.x * b.x; acc[0][1] += a.x * b.y; acc[0][2] += a.x * b.z; acc[0][3] += a.x * b.w;
            acc[1][0] += a.y * b.x; acc[1][1] += a.y * b.y; acc[1][2] += a.y * b.z; acc[1][3] += a.y * b.w;
            acc[2][0] += a.z * b.x; acc[2][1] += a.z * b.y; acc[2][2] += a.z * b.z; acc[2][3] += a.z * b.w;
            acc[3][0] += a.w * b.x; acc[3][1] += a.w * b.y; acc[3][2] += a.w * b.z; acc[3][3] += a.w * b.w;
        }
        __syncthreads();
    }

#pragma unroll
    for (int i = 0; i < 4; ++i) {
        const int r = r0 + ty * 4 + i;
#pragma unroll
        for (int j = 0; j < 4; ++j) {
            const int n = n0 + tx * 4 + j;
            float v = acc[i][j];
            if constexpr (EPI != 3) v += bias[n];
            v += resid[(size_t)r * N + n];
            ((float*)out)[(size_t)r * N + n] = v;
        }
    }
}

// ---------------- MFMA flash attention ----------------
// grid (32 qtiles, 32 bh), 256 threads = 4 waves; wave owns 16 q rows.
// K_lds[k][d], Vt_lds[d][k] both 64x64 bf16 swizzled; P per-wave [16 q][64 k].
__global__ __launch_bounds__(256) void attn_mfma_k(const u16* __restrict__ Kb,
                                                   const u16* __restrict__ Qb,
                                                   const u16* __restrict__ Vb,
                                                   u16* __restrict__ agg) {
    __shared__ alignas(16) u16 Kl[64 * 64];
    __shared__ alignas(16) u16 Vt[64 * 64];
    __shared__ alignas(16) u16 Pl[4][16 * 64];

    const int tid = threadIdx.x;
    const int lane = tid & 63;
    const int w = tid >> 6;
    const int g = lane >> 4;   // 0..3
    const int c = lane & 15;   // 0..15

    const int qt = blockIdx.x;  // 0..31
    const int bh = blockIdx.y;  // 0..31
    const int b = bh >> 3, h = bh & 7;
    const int q0 = qt * 64 + w * 16;

    // Q A-frags: lane holds Q[q0 + c][ch*32 + g*8 + i], i=0..7
    const u16* Qbase = Qb + ((size_t)bh * T_ + q0) * D_;
    bf16x8 aq[2];
#pragma unroll
    for (int ch = 0; ch < 2; ++ch)
        aq[ch] = *(const bf16x8*)(Qbase + (size_t)c * D_ + ch * 32 + g * 8);

    f32x4 Oacc[4] = {};       // d-blocks of 16
    float m_r[4], l_r[4];
#pragma unroll
    for (int r = 0; r < 4; ++r) { m_r[r] = -1e30f; l_r[r] = 0.f; }

    const u16* Kbh = Kb + (size_t)bh * T_ * D_;
    const u16* Vbh = Vb + (size_t)bh * T_ * D_;
    char* KlB = (char*)Kl;
    char* VtB = (char*)Vt;
    char* PlB = (char*)Pl[w];

    for (int j0 = 0; j0 < T_; j0 += 64) {
        // ---- stage K tile [64][64] (swizzled rows) + V^T tile [d][k] ----
#pragma unroll
        for (int it = 0; it < 2; ++it) {
            const int e = (it * 256 + tid) * 8;
            const int kr = e >> 6, dc = e & 63;
            bf16x8 k8 = *(const bf16x8*)(Kbh + (size_t)(j0 + kr) * D_ + dc);
            *(bf16x8*)(KlB + kr * 128 + ((dc * 2) ^ ((kr & 7) << 4))) = k8;
            bf16x8 v8 = *(const bf16x8*)(Vbh + (size_t)(j0 + kr) * D_ + dc);
#pragma unroll
            for (int i2 = 0; i2 < 8; ++i2) {
                const int d = dc + i2;
                *(u16*)(VtB + d * 128 + ((kr * 2) ^ ((d & 7) << 4))) =
                    ((const u16*)&v8)[i2];
            }
        }
        __syncthreads();

        // ---- S = Q K^T (per wave 16x64) ----
        f32x4 s[4] = {};
#pragma unroll
        for (int nb = 0; nb < 4; ++nb) {
            const int krow = nb * 16 + c;
#pragma unroll
            for (int ch = 0; ch < 2; ++ch) {
                bf16x8 bk = *(const bf16x8*)(
                    KlB + krow * 128 + (((ch * 32 + g * 8) * 2) ^ ((krow & 7) << 4)));
                s[nb] = __builtin_amdgcn_mfma_f32_16x16x32_bf16(aq[ch], bk, s[nb], 0, 0, 0);
            }
        }
#pragma unroll
        for (int nb = 0; nb < 4; ++nb) s[nb] *= 0.125f;

        // ---- online softmax (rows = g*4+r, cols spread over 16 lanes x 4 nb) ----
#pragma unroll
        for (int r = 0; r < 4; ++r) {
            float mx = fmaxf(fmaxf(s[0][r], s[1][r]), fmaxf(s[2][r], s[3][r]));
#pragma unroll
            for (int off = 1; off < 16; off <<= 1)
                mx = fmaxf(mx, __shfl_xor(mx, off, 64));
            const float mnew = fmaxf(m_r[r], mx);
            const float corr = __expf(m_r[r] - mnew);
            const int q = g * 4 + r;
            float rs = 0.f;
#pragma unroll
            for (int nb = 0; nb < 4; ++nb) {
                float p = __expf(s[nb][r] - mnew);
                rs += p;
                const int colb = (c + 16 * nb) * 2;
                *(u16*)(PlB + q * 128 + (colb ^ ((q & 7) << 4))) = f2b(p);
            }
#pragma unroll
            for (int off = 1; off < 16; off <<= 1)
                rs += __shfl_xor(rs, off, 64);
            l_r[r] = l_r[r] * corr + rs;
            m_r[r] = mnew;
#pragma unroll
            for (int db = 0; db < 4; ++db) Oacc[db][r] *= corr;
        }

        // ---- O += P V (per wave) ----
#pragma unroll
        for (int db = 0; db < 4; ++db) {
            const int drow = db * 16 + c;
#pragma unroll
            for (int ch = 0; ch < 2; ++ch) {
                bf16x8 ap = *(const bf16x8*)(
                    PlB + c * 128 + (((ch * 32 + g * 8) * 2) ^ ((c & 7) << 4)));
                bf16x8 bv = *(const bf16x8*)(
                    VtB + drow * 128 + (((ch * 32 + g * 8) * 2) ^ ((drow & 7) << 4)));
                Oacc[db] = __builtin_amdgcn_mfma_f32_16x16x32_bf16(ap, bv, Oacc[db], 0, 0, 0);
            }
        }
        __syncthreads();
    }

    // ---- normalize + write agg[b][t][h*64+d] ----
#pragma unroll
    for (int r = 0; r < 4; ++r) {
        const float inv = 1.0f / l_r[r];
        const size_t row = (size_t)b * T_ + q0 + g * 4 + r;
#pragma unroll
        for (int db = 0; db < 4; ++db) {
            agg[row * C_ + h * D_ + db * 16 + c] = f2b(Oacc[db][r] * inv);
        }
    }
}

// ---------------- launch ----------------
extern "C" void kernel_launch(void* const* d_in, const int* in_sizes, int n_in,
                              void* d_out, int out_size, void* d_ws, size_t ws_size,
                              hipStream_t stream) {
    (void)in_sizes; (void)n_in; (void)out_size; (void)ws_size;
    const float* x       = (const float*)d_in[0];
    const float* w_kqv   = (const float*)d_in[1];
    const float* b_kqv   = (const float*)d_in[2];
    const float* w_proj  = (const float*)d_in[3];
    const float* b_proj  = (const float*)d_in[4];
    const float* w_fc    = (const float*)d_in[5];
    const float* b_fc    = (const float*)d_in[6];
    const float* w_cproj = (const float*)d_in[7];

    char* ws = (char*)d_ws;
    float* stats = (float*)ws;                                   // 64 KB
    u16* kqv = (u16*)(ws + 65536);                               // 3 * 8 MB
    u16* agg = (u16*)(ws + 65536 + 3ull * KQV_SEC * 2);          // 8 MB
    float* x2 = (float*)(ws + 65536 + 3ull * KQV_SEC * 2 + (size_t)BT * C_ * 2); // 16 MB
    u16* hbuf = (u16*)((char*)x2 + (size_t)BT * C_ * 4);         // 16 MB

    // 1) ln1 stats on x
    ln_stats_k<<<BT, 256, 0, stream>>>(x, stats);
    // 2) kqv = ln(x) @ w_kqv^T + b_kqv, scattered to k/q/v [B*H][T][64] (bf16)
    gemm64<1, 0><<<dim3(1536 / 64, BT / 64), 256, 0, stream>>>(
        x, w_kqv, b_kqv, stats, nullptr, kqv, 512);
    // 3) MFMA flash attention -> agg (B,T,C) bf16
    attn_mfma_k<<<dim3(T_ / 64, B_ * H_), 256, 0, stream>>>(
        kqv, kqv + KQV_SEC, kqv + 2 * KQV_SEC, agg);
    // 4) x2 = x + agg @ w_proj^T + b_proj   (f32)
    gemm64b<1><<<dim3(512 / 64, BT / 64), 256, 0, stream>>>(
        agg, w_proj, b_proj, x, x2, 512);
    // 5) ln2 stats on x2
    ln_stats_k<<<BT, 256, 0, stream>>>(x2, stats);
    // 6) h = gelu(ln(x2) @ w_fc^T + b_fc)   (bf16)
    gemm64<1, 2><<<dim3(1024 / 64, BT / 64), 256, 0, stream>>>(
        x2, w_fc, b_fc, stats, nullptr, hbuf, 512);
    // 7) out = x2 + h @ w_cproj^T           (f32)
    gemm64b<3><<<dim3(512 / 64, BT / 64), 256, 0, stream>>>(
        hbuf, w_cproj, nullptr, x2, d_out, 1024);
}

// Round 4
// 284.572 us; speedup vs baseline: 15.7286x; 2.3444x over previous
//
#include <hip/hip_runtime.h>
#include <hip/hip_bf16.h>
#include <cmath>

// TransformerBlock  B=4 T=2048 C=512 H=8 D=64  (f32 I/O, bf16 MFMA internal)

using u16 = unsigned short;
typedef __attribute__((ext_vector_type(4))) float f32x4;
typedef __attribute__((ext_vector_type(8))) short bf16x8;

constexpr int B_ = 4, T_ = 2048, C_ = 512, H_ = 8, D_ = 64;
constexpr int BT = B_ * T_;                // 8192 rows
constexpr int KQV_SEC = B_ * H_ * T_ * D_; // 4194304 elems per k/q/v section

__device__ __forceinline__ float b2f(u16 u) {
    return __uint_as_float(((unsigned)u) << 16);
}
__device__ __forceinline__ u16 f2b(float f) {
    __hip_bfloat16 h = __float2bfloat16(f);
    return *reinterpret_cast<u16*>(&h);
}

// async global->LDS, 16B per lane; LDS dest = wave-uniform base + lane*16
__device__ __forceinline__ void gl_lds16(const u16* g, u16* l) {
    __builtin_amdgcn_global_load_lds(
        (const __attribute__((address_space(1))) unsigned int*)(const void*)g,
        (__attribute__((address_space(3))) unsigned int*)(void*)l, 16, 0, 0);
}

// ---------------- weight f32 -> bf16 ----------------
__global__ __launch_bounds__(256) void wcvt_k(const float* __restrict__ w,
                                              u16* __restrict__ o, int n4) {
    const int i = blockIdx.x * 256 + threadIdx.x;
    if (i < n4) {
        float4 v = ((const float4*)w)[i];
        ushort4 u;
        u.x = f2b(v.x); u.y = f2b(v.y); u.z = f2b(v.z); u.w = f2b(v.w);
        ((ushort4*)o)[i] = u;
    }
}

// ---------------- fused LayerNorm: f32 in -> bf16 normalized out ----------------
__global__ __launch_bounds__(256) void ln_fused_k(const float* __restrict__ x,
                                                  u16* __restrict__ o) {
    const int r = blockIdx.x;
    const int t = threadIdx.x;
    const float v0 = x[(size_t)r * C_ + t];
    const float v1 = x[(size_t)r * C_ + t + 256];
    __shared__ float rs[256], rq[256];
    rs[t] = v0 + v1;
    rq[t] = v0 * v0 + v1 * v1;
    __syncthreads();
    for (int k = 128; k; k >>= 1) {
        if (t < k) { rs[t] += rs[t + k]; rq[t] += rq[t + k]; }
        __syncthreads();
    }
    __shared__ float sm, sr;
    if (t == 0) {
        float m = rs[0] * (1.0f / C_);
        float var = rq[0] * (1.0f / C_) - m * m;
        sm = m;
        sr = rsqrtf(var + 1e-5f);
    }
    __syncthreads();
    const float m = sm, rstd = sr;
    o[(size_t)r * C_ + t] = f2b((v0 - m) * rstd);
    o[(size_t)r * C_ + t + 256] = f2b((v1 - m) * rstd);
}

// ---------------- MFMA GEMM: out = A(bf16 [M][K]) @ W(bf16 [N][K])^T ----------------
// 128x128 tile, BK=64, 4 waves each 64x64. global_load_lds staging with
// inverse-swizzled global source (rule #21): LDS row r holds data col-byte
// cb at offset cb ^ ((r&7)<<4).
// EPI: 0 kqv scatter(+bias,bf16) | 1 +bias+resid(f32)->f32 | 2 +bias,gelu->bf16 | 3 +resid->f32
template <int EPI>
__global__ __launch_bounds__(256) void gemm_mfma(const u16* __restrict__ A,
                                                 const u16* __restrict__ W,
                                                 const float* __restrict__ bias,
                                                 const float* __restrict__ resid,
                                                 void* __restrict__ out,
                                                 int K, int N) {
    __shared__ alignas(16) u16 Al[128 * 64];
    __shared__ alignas(16) u16 Bl[128 * 64];
    const int tid = threadIdx.x, lane = tid & 63, w = tid >> 6;
    const int g = lane >> 4, c = lane & 15;
    const int wm = w >> 1, wn = w & 1;
    const int n0 = blockIdx.x * 128, r0 = blockIdx.y * 128;

    const int l7 = lane & 7, l3 = lane >> 3;
    const int colHalf = ((l7 ^ l3) << 3);   // swizzled source column (elements)

    f32x4 acc[4][4] = {};
    const char* AlB = (const char*)Al;
    const char* BlB = (const char*)Bl;

    for (int kk = 0; kk < K; kk += 64) {
        // stage A+B tiles: wave w -> segments w*4..w*4+3 (1 KB = 8 rows each)
#pragma unroll
        for (int i = 0; i < 4; ++i) {
            const int s = w * 4 + i;
            const int row = s * 8 + l3;
            gl_lds16(A + (size_t)(r0 + row) * K + kk + colHalf, &Al[s * 512]);
            gl_lds16(W + (size_t)(n0 + row) * K + kk + colHalf, &Bl[s * 512]);
        }
        __syncthreads();

        bf16x8 af[4][2], bf[4][2];
#pragma unroll
        for (int mf = 0; mf < 4; ++mf) {
            const int ar = wm * 64 + mf * 16 + c;
#pragma unroll
            for (int ch = 0; ch < 2; ++ch)
                af[mf][ch] = *(const bf16x8*)(
                    AlB + ar * 128 + (((ch * 32 + g * 8) * 2) ^ ((ar & 7) << 4)));
        }
#pragma unroll
        for (int nf = 0; nf < 4; ++nf) {
            const int br = wn * 64 + nf * 16 + c;
#pragma unroll
            for (int ch = 0; ch < 2; ++ch)
                bf[nf][ch] = *(const bf16x8*)(
                    BlB + br * 128 + (((ch * 32 + g * 8) * 2) ^ ((br & 7) << 4)));
        }
#pragma unroll
        for (int mf = 0; mf < 4; ++mf)
#pragma unroll
            for (int nf = 0; nf < 4; ++nf)
#pragma unroll
                for (int ch = 0; ch < 2; ++ch)
                    acc[mf][nf] = __builtin_amdgcn_mfma_f32_16x16x32_bf16(
                        af[mf][ch], bf[nf][ch], acc[mf][nf], 0, 0, 0);
        __syncthreads();
    }

    // epilogue: C/D layout col=lane&15, row=(lane>>4)*4+reg
#pragma unroll
    for (int mf = 0; mf < 4; ++mf) {
#pragma unroll
        for (int nf = 0; nf < 4; ++nf) {
#pragma unroll
            for (int r = 0; r < 4; ++r) {
                const int rr = r0 + wm * 64 + mf * 16 + g * 4 + r;
                const int nn = n0 + wn * 64 + nf * 16 + c;
                float v = acc[mf][nf][r];
                if constexpr (EPI != 3) v += bias[nn];
                if constexpr (EPI == 0) {
                    const int s = nn >> 9, rem = nn & 511;
                    const int h = rem >> 6, dd = rem & 63;
                    const int b = rr >> 11, t = rr & 2047;
                    ((u16*)out)[(size_t)s * KQV_SEC +
                                (((size_t)(b * H_ + h) * T_ + t) * D_ + dd)] = f2b(v);
                } else if constexpr (EPI == 1) {
                    v += resid[(size_t)rr * N + nn];
                    ((float*)out)[(size_t)rr * N + nn] = v;
                } else if constexpr (EPI == 2) {
                    float ge = 0.5f * v * (1.0f + erff(v * 0.70710678118654752f));
                    ((u16*)out)[(size_t)rr * N + nn] = f2b(ge);
                } else {
                    v += resid[(size_t)rr * N + nn];
                    ((float*)out)[(size_t)rr * N + nn] = v;
                }
            }
        }
    }
}

// ---------------- MFMA flash attention (unchanged from round 3) ----------------
__global__ __launch_bounds__(256) void attn_mfma_k(const u16* __restrict__ Kb,
                                                   const u16* __restrict__ Qb,
                                                   const u16* __restrict__ Vb,
                                                   u16* __restrict__ agg) {
    __shared__ alignas(16) u16 Kl[64 * 64];
    __shared__ alignas(16) u16 Vt[64 * 64];
    __shared__ alignas(16) u16 Pl[4][16 * 64];

    const int tid = threadIdx.x;
    const int lane = tid & 63;
    const int w = tid >> 6;
    const int g = lane >> 4;
    const int c = lane & 15;

    const int qt = blockIdx.x;
    const int bh = blockIdx.y;
    const int b = bh >> 3, h = bh & 7;
    const int q0 = qt * 64 + w * 16;

    const u16* Qbase = Qb + ((size_t)bh * T_ + q0) * D_;
    bf16x8 aq[2];
#pragma unroll
    for (int ch = 0; ch < 2; ++ch)
        aq[ch] = *(const bf16x8*)(Qbase + (size_t)c * D_ + ch * 32 + g * 8);

    f32x4 Oacc[4] = {};
    float m_r[4], l_r[4];
#pragma unroll
    for (int r = 0; r < 4; ++r) { m_r[r] = -1e30f; l_r[r] = 0.f; }

    const u16* Kbh = Kb + (size_t)bh * T_ * D_;
    const u16* Vbh = Vb + (size_t)bh * T_ * D_;
    char* KlB = (char*)Kl;
    char* VtB = (char*)Vt;
    char* PlB = (char*)Pl[w];

    for (int j0 = 0; j0 < T_; j0 += 64) {
#pragma unroll
        for (int it = 0; it < 2; ++it) {
            const int e = (it * 256 + tid) * 8;
            const int kr = e >> 6, dc = e & 63;
            bf16x8 k8 = *(const bf16x8*)(Kbh + (size_t)(j0 + kr) * D_ + dc);
            *(bf16x8*)(KlB + kr * 128 + ((dc * 2) ^ ((kr & 7) << 4))) = k8;
            bf16x8 v8 = *(const bf16x8*)(Vbh + (size_t)(j0 + kr) * D_ + dc);
#pragma unroll
            for (int i2 = 0; i2 < 8; ++i2) {
                const int d = dc + i2;
                *(u16*)(VtB + d * 128 + ((kr * 2) ^ ((d & 7) << 4))) =
                    ((const u16*)&v8)[i2];
            }
        }
        __syncthreads();

        f32x4 s[4] = {};
#pragma unroll
        for (int nb = 0; nb < 4; ++nb) {
            const int krow = nb * 16 + c;
#pragma unroll
            for (int ch = 0; ch < 2; ++ch) {
                bf16x8 bk = *(const bf16x8*)(
                    KlB + krow * 128 + (((ch * 32 + g * 8) * 2) ^ ((krow & 7) << 4)));
                s[nb] = __builtin_amdgcn_mfma_f32_16x16x32_bf16(aq[ch], bk, s[nb], 0, 0, 0);
            }
        }
#pragma unroll
        for (int nb = 0; nb < 4; ++nb) s[nb] *= 0.125f;

#pragma unroll
        for (int r = 0; r < 4; ++r) {
            float mx = fmaxf(fmaxf(s[0][r], s[1][r]), fmaxf(s[2][r], s[3][r]));
#pragma unroll
            for (int off = 1; off < 16; off <<= 1)
                mx = fmaxf(mx, __shfl_xor(mx, off, 64));
            const float mnew = fmaxf(m_r[r], mx);
            const float corr = __expf(m_r[r] - mnew);
            const int q = g * 4 + r;
            float rs = 0.f;
#pragma unroll
            for (int nb = 0; nb < 4; ++nb) {
                float p = __expf(s[nb][r] - mnew);
                rs += p;
                const int colb = (c + 16 * nb) * 2;
                *(u16*)(PlB + q * 128 + (colb ^ ((q & 7) << 4))) = f2b(p);
            }
#pragma unroll
            for (int off = 1; off < 16; off <<= 1)
                rs += __shfl_xor(rs, off, 64);
            l_r[r] = l_r[r] * corr + rs;
            m_r[r] = mnew;
#pragma unroll
            for (int db = 0; db < 4; ++db) Oacc[db][r] *= corr;
        }

#pragma unroll
        for (int db = 0; db < 4; ++db) {
            const int drow = db * 16 + c;
#pragma unroll
            for (int ch = 0; ch < 2; ++ch) {
                bf16x8 ap = *(const bf16x8*)(
                    PlB + c * 128 + (((ch * 32 + g * 8) * 2) ^ ((c & 7) << 4)));
                bf16x8 bv = *(const bf16x8*)(
                    VtB + drow * 128 + (((ch * 32 + g * 8) * 2) ^ ((drow & 7) << 4)));
                Oacc[db] = __builtin_amdgcn_mfma_f32_16x16x32_bf16(ap, bv, Oacc[db], 0, 0, 0);
            }
        }
        __syncthreads();
    }

#pragma unroll
    for (int r = 0; r < 4; ++r) {
        const float inv = 1.0f / l_r[r];
        const size_t row = (size_t)b * T_ + q0 + g * 4 + r;
#pragma unroll
        for (int db = 0; db < 4; ++db) {
            agg[row * C_ + h * D_ + db * 16 + c] = f2b(Oacc[db][r] * inv);
        }
    }
}

// ---------------- launch ----------------
extern "C" void kernel_launch(void* const* d_in, const int* in_sizes, int n_in,
                              void* d_out, int out_size, void* d_ws, size_t ws_size,
                              hipStream_t stream) {
    (void)in_sizes; (void)n_in; (void)out_size; (void)ws_size;
    const float* x       = (const float*)d_in[0];
    const float* w_kqv   = (const float*)d_in[1];
    const float* b_kqv   = (const float*)d_in[2];
    const float* w_proj  = (const float*)d_in[3];
    const float* b_proj  = (const float*)d_in[4];
    const float* w_fc    = (const float*)d_in[5];
    const float* b_fc    = (const float*)d_in[6];
    const float* w_cproj = (const float*)d_in[7];

    char* ws = (char*)d_ws;
    u16* wq_b = (u16*)(ws + 0);                    // 1536*512  -> 1.5 MB
    u16* wp_b = (u16*)(ws + (1536 * 512) * 2);     // 512*512   -> 0.5 MB
    u16* wf_b = (u16*)(ws + (1536 * 512 + 512 * 512) * 2);           // 1 MB
    u16* wc_b = (u16*)(ws + (1536 * 512 + 512 * 512 + 1024 * 512) * 2); // 1 MB
    u16* lnbuf = (u16*)(ws + (4ull << 20));        // 8 MB (ln1 then ln2 output)
    u16* kqv  = (u16*)(ws + (12ull << 20));        // 24 MB
    u16* hbuf = (u16*)(ws + (12ull << 20));        // overlays kqv (dead after attn)
    u16* agg  = (u16*)(ws + (36ull << 20));        // 8 MB
    float* x2 = (float*)(ws + (44ull << 20));      // 16 MB

    // weights -> bf16
    wcvt_k<<<(1536 * 512 / 4 + 255) / 256, 256, 0, stream>>>(w_kqv, wq_b, 1536 * 512 / 4);
    wcvt_k<<<(512 * 512 / 4 + 255) / 256, 256, 0, stream>>>(w_proj, wp_b, 512 * 512 / 4);
    wcvt_k<<<(1024 * 512 / 4 + 255) / 256, 256, 0, stream>>>(w_fc, wf_b, 1024 * 512 / 4);
    wcvt_k<<<(512 * 1024 / 4 + 255) / 256, 256, 0, stream>>>(w_cproj, wc_b, 512 * 1024 / 4);

    // ln1 -> bf16
    ln_fused_k<<<BT, 256, 0, stream>>>(x, lnbuf);
    // kqv = ln1(x) @ w_kqv^T + b_kqv  -> scatter bf16 k/q/v
    gemm_mfma<0><<<dim3(1536 / 128, BT / 128), 256, 0, stream>>>(
        lnbuf, wq_b, b_kqv, nullptr, kqv, 512, 1536);
    // attention
    attn_mfma_k<<<dim3(T_ / 64, B_ * H_), 256, 0, stream>>>(
        kqv, kqv + KQV_SEC, kqv + 2 * KQV_SEC, agg);
    // x2 = x + agg @ w_proj^T + b_proj   (f32)
    gemm_mfma<1><<<dim3(512 / 128, BT / 128), 256, 0, stream>>>(
        agg, wp_b, b_proj, x, x2, 512, 512);
    // ln2 -> bf16
    ln_fused_k<<<BT, 256, 0, stream>>>(x2, lnbuf);
    // h = gelu(ln2(x2) @ w_fc^T + b_fc)  (bf16)
    gemm_mfma<2><<<dim3(1024 / 128, BT / 128), 256, 0, stream>>>(
        lnbuf, wf_b, b_fc, nullptr, hbuf, 512, 1024);
    // out = x2 + h @ w_cproj^T           (f32)
    gemm_mfma<3><<<dim3(512 / 128, BT / 128), 256, 0, stream>>>(
        hbuf, wc_b, nullptr, x2, d_out, 1024, 512);
}

// Round 5
// 232.461 us; speedup vs baseline: 19.2545x; 1.2242x over previous
//
#include <hip/hip_runtime.h>
#include <hip/hip_bf16.h>
#include <cmath>

// TransformerBlock  B=4 T=2048 C=512 H=8 D=64  (f32 I/O, bf16 MFMA internal)

using u16 = unsigned short;
typedef __attribute__((ext_vector_type(4))) float f32x4;
typedef __attribute__((ext_vector_type(8))) short bf16x8;

constexpr int B_ = 4, T_ = 2048, C_ = 512, H_ = 8, D_ = 64;
constexpr int BT = B_ * T_;                // 8192 rows
constexpr int KQV_SEC = B_ * H_ * T_ * D_; // 4194304 elems per k/q/v section

__device__ __forceinline__ float b2f(u16 u) {
    return __uint_as_float(((unsigned)u) << 16);
}
__device__ __forceinline__ u16 f2b(float f) {
    __hip_bfloat16 h = __float2bfloat16(f);
    return *reinterpret_cast<u16*>(&h);
}

// async global->LDS, 16B per lane; LDS dest = wave-uniform base + lane*16
__device__ __forceinline__ void gl_lds16(const u16* g, u16* l) {
    __builtin_amdgcn_global_load_lds(
        (const __attribute__((address_space(1))) unsigned int*)(const void*)g,
        (__attribute__((address_space(3))) unsigned int*)(void*)l, 16, 0, 0);
}

// ---------------- all weights f32 -> bf16, one launch ----------------
__global__ __launch_bounds__(256) void wcvt_all_k(const float* __restrict__ w0,
                                                  const float* __restrict__ w1,
                                                  const float* __restrict__ w2,
                                                  const float* __restrict__ w3,
                                                  u16* __restrict__ o0,
                                                  u16* __restrict__ o1,
                                                  u16* __restrict__ o2,
                                                  u16* __restrict__ o3) {
    // sizes in float4 units: 196608 | 65536 | 131072 | 131072  (total 524288)
    const int i = blockIdx.x * 256 + threadIdx.x;
    const float* w; u16* o; int j;
    if (i < 196608) { w = w0; o = o0; j = i; }
    else if (i < 262144) { w = w1; o = o1; j = i - 196608; }
    else if (i < 393216) { w = w2; o = o2; j = i - 262144; }
    else { w = w3; o = o3; j = i - 393216; }
    float4 v = ((const float4*)w)[j];
    ushort4 u;
    u.x = f2b(v.x); u.y = f2b(v.y); u.z = f2b(v.z); u.w = f2b(v.w);
    ((ushort4*)o)[j] = u;
}

// ---------------- fused LayerNorm: f32 in -> bf16 normalized out ----------------
__global__ __launch_bounds__(256) void ln_fused_k(const float* __restrict__ x,
                                                  u16* __restrict__ o) {
    const int r = blockIdx.x;
    const int t = threadIdx.x;
    const float v0 = x[(size_t)r * C_ + t];
    const float v1 = x[(size_t)r * C_ + t + 256];
    __shared__ float rs[256], rq[256];
    rs[t] = v0 + v1;
    rq[t] = v0 * v0 + v1 * v1;
    __syncthreads();
    for (int k = 128; k; k >>= 1) {
        if (t < k) { rs[t] += rs[t + k]; rq[t] += rq[t + k]; }
        __syncthreads();
    }
    __shared__ float sm, sr;
    if (t == 0) {
        float m = rs[0] * (1.0f / C_);
        float var = rq[0] * (1.0f / C_) - m * m;
        sm = m;
        sr = rsqrtf(var + 1e-5f);
    }
    __syncthreads();
    const float m = sm, rstd = sr;
    o[(size_t)r * C_ + t] = f2b((v0 - m) * rstd);
    o[(size_t)r * C_ + t + 256] = f2b((v1 - m) * rstd);
}

// ---------------- MFMA GEMM: out = A(bf16 [M][K]) @ W(bf16 [N][K])^T ----------------
// 128x128 tile, BK=64, 4 waves each 64x64. global_load_lds staging with
// inverse-swizzled global source (rule #21).
// EPI: 0 kqv scatter (+bias, bf16; V section written TRANSPOSED [bh][d][T])
//      1 +bias+resid(f32)->f32 | 2 +bias,gelu->bf16 | 3 +resid->f32
template <int EPI>
__global__ __launch_bounds__(256) void gemm_mfma(const u16* __restrict__ A,
                                                 const u16* __restrict__ W,
                                                 const float* __restrict__ bias,
                                                 const float* __restrict__ resid,
                                                 void* __restrict__ out,
                                                 int K, int N) {
    __shared__ alignas(16) u16 Al[128 * 64];
    __shared__ alignas(16) u16 Bl[128 * 64];
    const int tid = threadIdx.x, lane = tid & 63, w = tid >> 6;
    const int g = lane >> 4, c = lane & 15;
    const int wm = w >> 1, wn = w & 1;
    const int n0 = blockIdx.x * 128, r0 = blockIdx.y * 128;

    const int l7 = lane & 7, l3 = lane >> 3;
    const int colHalf = ((l7 ^ l3) << 3);   // swizzled source column (elements)

    f32x4 acc[4][4] = {};
    const char* AlB = (const char*)Al;
    const char* BlB = (const char*)Bl;

    for (int kk = 0; kk < K; kk += 64) {
#pragma unroll
        for (int i = 0; i < 4; ++i) {
            const int s = w * 4 + i;
            const int row = s * 8 + l3;
            gl_lds16(A + (size_t)(r0 + row) * K + kk + colHalf, &Al[s * 512]);
            gl_lds16(W + (size_t)(n0 + row) * K + kk + colHalf, &Bl[s * 512]);
        }
        __syncthreads();

        bf16x8 af[4][2], bf[4][2];
#pragma unroll
        for (int mf = 0; mf < 4; ++mf) {
            const int ar = wm * 64 + mf * 16 + c;
#pragma unroll
            for (int ch = 0; ch < 2; ++ch)
                af[mf][ch] = *(const bf16x8*)(
                    AlB + ar * 128 + (((ch * 32 + g * 8) * 2) ^ ((ar & 7) << 4)));
        }
#pragma unroll
        for (int nf = 0; nf < 4; ++nf) {
            const int br = wn * 64 + nf * 16 + c;
#pragma unroll
            for (int ch = 0; ch < 2; ++ch)
                bf[nf][ch] = *(const bf16x8*)(
                    BlB + br * 128 + (((ch * 32 + g * 8) * 2) ^ ((br & 7) << 4)));
        }
#pragma unroll
        for (int mf = 0; mf < 4; ++mf)
#pragma unroll
            for (int nf = 0; nf < 4; ++nf)
#pragma unroll
                for (int ch = 0; ch < 2; ++ch)
                    acc[mf][nf] = __builtin_amdgcn_mfma_f32_16x16x32_bf16(
                        af[mf][ch], bf[nf][ch], acc[mf][nf], 0, 0, 0);
        __syncthreads();
    }

    // epilogue: C/D layout col=lane&15, row=(lane>>4)*4+reg
#pragma unroll
    for (int mf = 0; mf < 4; ++mf) {
#pragma unroll
        for (int nf = 0; nf < 4; ++nf) {
            const int nn = n0 + wn * 64 + nf * 16 + c;
            const int rb = r0 + wm * 64 + mf * 16 + g * 4;
            if constexpr (EPI == 0) {
                const int s = nn >> 9, rem = nn & 511;
                const int hh = rem >> 6, dd = rem & 63;
                const int bb = rb >> 11, t0 = rb & 2047;
                float v[4];
#pragma unroll
                for (int r = 0; r < 4; ++r) v[r] = acc[mf][nf][r] + bias[nn];
                if (s == 2) {
                    // V section: write transposed  vT[bh][d][T]
                    ushort4 u;
                    u.x = f2b(v[0]); u.y = f2b(v[1]); u.z = f2b(v[2]); u.w = f2b(v[3]);
                    *(ushort4*)((u16*)out + (size_t)2 * KQV_SEC +
                                (((size_t)(bb * H_ + hh) * D_ + dd) * T_ + t0)) = u;
                } else {
#pragma unroll
                    for (int r = 0; r < 4; ++r)
                        ((u16*)out)[(size_t)s * KQV_SEC +
                                    (((size_t)(bb * H_ + hh) * T_ + t0 + r) * D_ + dd)] = f2b(v[r]);
                }
            } else {
#pragma unroll
                for (int r = 0; r < 4; ++r) {
                    const int rr = rb + r;
                    float v = acc[mf][nf][r];
                    if constexpr (EPI != 3) v += bias[nn];
                    if constexpr (EPI == 1) {
                        v += resid[(size_t)rr * N + nn];
                        ((float*)out)[(size_t)rr * N + nn] = v;
                    } else if constexpr (EPI == 2) {
                        float ge = 0.5f * v * (1.0f + erff(v * 0.70710678118654752f));
                        ((u16*)out)[(size_t)rr * N + nn] = f2b(ge);
                    } else {
                        v += resid[(size_t)rr * N + nn];
                        ((float*)out)[(size_t)rr * N + nn] = v;
                    }
                }
            }
        }
    }
}

// ---------------- MFMA flash attention ----------------
// K section [bh][T][64]; V supplied pre-transposed vT [bh][64][T].
// Both staged via global_load_lds with inverse-swizzled source -> conflict-free
// swizzled ds_read_b128 fragments.
__global__ __launch_bounds__(256) void attn_mfma_k(const u16* __restrict__ Kb,
                                                   const u16* __restrict__ Qb,
                                                   const u16* __restrict__ VTb,
                                                   u16* __restrict__ agg) {
    __shared__ alignas(16) u16 Kl[64 * 64];
    __shared__ alignas(16) u16 Vt[64 * 64];
    __shared__ alignas(16) u16 Pl[4][16 * 64];

    const int tid = threadIdx.x;
    const int lane = tid & 63;
    const int w = tid >> 6;
    const int g = lane >> 4;
    const int c = lane & 15;
    const int l3 = lane >> 3, l7 = lane & 7;
    const int srcE = ((l7 ^ l3) << 3);      // swizzled source column (elements)

    const int qt = blockIdx.x;
    const int bh = blockIdx.y;
    const int b = bh >> 3, h = bh & 7;
    const int q0 = qt * 64 + w * 16;

    const u16* Qbase = Qb + ((size_t)bh * T_ + q0) * D_;
    bf16x8 aq[2];
#pragma unroll
    for (int ch = 0; ch < 2; ++ch)
        aq[ch] = *(const bf16x8*)(Qbase + (size_t)c * D_ + ch * 32 + g * 8);

    f32x4 Oacc[4] = {};
    float m_r[4], l_r[4];
#pragma unroll
    for (int r = 0; r < 4; ++r) { m_r[r] = -1e30f; l_r[r] = 0.f; }

    const u16* Kbh = Kb + (size_t)bh * T_ * D_;
    const u16* VTbh = VTb + (size_t)bh * D_ * T_;
    const char* KlB = (const char*)Kl;
    const char* VtB = (const char*)Vt;
    char* PlB = (char*)Pl[w];

    for (int j0 = 0; j0 < T_; j0 += 64) {
        // ---- stage K tile [k][d] and V^T tile [d][k], 2 gl_lds16 each per wave ----
#pragma unroll
        for (int i = 0; i < 2; ++i) {
            const int row0 = w * 16 + i * 8;
            gl_lds16(Kbh + (size_t)(j0 + row0 + l3) * D_ + srcE, &Kl[row0 * 64]);
            gl_lds16(VTbh + (size_t)(row0 + l3) * T_ + j0 + srcE, &Vt[row0 * 64]);
        }
        __syncthreads();

        // ---- S = Q K^T (per wave 16x64) ----
        f32x4 s[4] = {};
#pragma unroll
        for (int nb = 0; nb < 4; ++nb) {
            const int krow = nb * 16 + c;
#pragma unroll
            for (int ch = 0; ch < 2; ++ch) {
                bf16x8 bk = *(const bf16x8*)(
                    KlB + krow * 128 + (((ch * 32 + g * 8) * 2) ^ ((krow & 7) << 4)));
                s[nb] = __builtin_amdgcn_mfma_f32_16x16x32_bf16(aq[ch], bk, s[nb], 0, 0, 0);
            }
        }
#pragma unroll
        for (int nb = 0; nb < 4; ++nb) s[nb] *= 0.125f;

        // ---- online softmax ----
#pragma unroll
        for (int r = 0; r < 4; ++r) {
            float mx = fmaxf(fmaxf(s[0][r], s[1][r]), fmaxf(s[2][r], s[3][r]));
#pragma unroll
            for (int off = 1; off < 16; off <<= 1)
                mx = fmaxf(mx, __shfl_xor(mx, off, 64));
            const float mnew = fmaxf(m_r[r], mx);
            const float corr = __expf(m_r[r] - mnew);
            const int q = g * 4 + r;
            float rs = 0.f;
#pragma unroll
            for (int nb = 0; nb < 4; ++nb) {
                float p = __expf(s[nb][r] - mnew);
                rs += p;
                const int colb = (c + 16 * nb) * 2;
                *(u16*)(PlB + q * 128 + (colb ^ ((q & 7) << 4))) = f2b(p);
            }
#pragma unroll
            for (int off = 1; off < 16; off <<= 1)
                rs += __shfl_xor(rs, off, 64);
            l_r[r] = l_r[r] * corr + rs;
            m_r[r] = mnew;
#pragma unroll
            for (int db = 0; db < 4; ++db) Oacc[db][r] *= corr;
        }

        // ---- O += P V ----
#pragma unroll
        for (int db = 0; db < 4; ++db) {
            const int drow = db * 16 + c;
#pragma unroll
            for (int ch = 0; ch < 2; ++ch) {
                bf16x8 ap = *(const bf16x8*)(
                    PlB + c * 128 + (((ch * 32 + g * 8) * 2) ^ ((c & 7) << 4)));
                bf16x8 bv = *(const bf16x8*)(
                    VtB + drow * 128 + (((ch * 32 + g * 8) * 2) ^ ((drow & 7) << 4)));
                Oacc[db] = __builtin_amdgcn_mfma_f32_16x16x32_bf16(ap, bv, Oacc[db], 0, 0, 0);
            }
        }
        __syncthreads();
    }

#pragma unroll
    for (int r = 0; r < 4; ++r) {
        const float inv = 1.0f / l_r[r];
        const size_t row = (size_t)b * T_ + q0 + g * 4 + r;
#pragma unroll
        for (int db = 0; db < 4; ++db) {
            agg[row * C_ + h * D_ + db * 16 + c] = f2b(Oacc[db][r] * inv);
        }
    }
}

// ---------------- launch ----------------
extern "C" void kernel_launch(void* const* d_in, const int* in_sizes, int n_in,
                              void* d_out, int out_size, void* d_ws, size_t ws_size,
                              hipStream_t stream) {
    (void)in_sizes; (void)n_in; (void)out_size; (void)ws_size;
    const float* x       = (const float*)d_in[0];
    const float* w_kqv   = (const float*)d_in[1];
    const float* b_kqv   = (const float*)d_in[2];
    const float* w_proj  = (const float*)d_in[3];
    const float* b_proj  = (const float*)d_in[4];
    const float* w_fc    = (const float*)d_in[5];
    const float* b_fc    = (const float*)d_in[6];
    const float* w_cproj = (const float*)d_in[7];

    char* ws = (char*)d_ws;
    u16* wq_b = (u16*)(ws + 0);                    // 1.5 MB
    u16* wp_b = (u16*)(ws + (1536 * 512) * 2);     // 0.5 MB
    u16* wf_b = (u16*)(ws + (1536 * 512 + 512 * 512) * 2);              // 1 MB
    u16* wc_b = (u16*)(ws + (1536 * 512 + 512 * 512 + 1024 * 512) * 2); // 1 MB
    u16* lnbuf = (u16*)(ws + (4ull << 20));        // 8 MB (ln1 then ln2 output)
    u16* kqv  = (u16*)(ws + (12ull << 20));        // 24 MB (K,Q sections + vT)
    u16* hbuf = (u16*)(ws + (12ull << 20));        // overlays kqv (dead after attn)
    u16* agg  = (u16*)(ws + (36ull << 20));        // 8 MB
    float* x2 = (float*)(ws + (44ull << 20));      // 16 MB

    // all weights -> bf16 (one launch)
    wcvt_all_k<<<524288 / 256, 256, 0, stream>>>(
        w_kqv, w_proj, w_fc, w_cproj, wq_b, wp_b, wf_b, wc_b);

    // ln1 -> bf16
    ln_fused_k<<<BT, 256, 0, stream>>>(x, lnbuf);
    // kqv = ln1(x) @ w_kqv^T + b_kqv  -> K,Q scattered [bh][T][64]; V transposed [bh][64][T]
    gemm_mfma<0><<<dim3(1536 / 128, BT / 128), 256, 0, stream>>>(
        lnbuf, wq_b, b_kqv, nullptr, kqv, 512, 1536);
    // attention
    attn_mfma_k<<<dim3(T_ / 64, B_ * H_), 256, 0, stream>>>(
        kqv, kqv + KQV_SEC, kqv + 2 * KQV_SEC, agg);
    // x2 = x + agg @ w_proj^T + b_proj   (f32)
    gemm_mfma<1><<<dim3(512 / 128, BT / 128), 256, 0, stream>>>(
        agg, wp_b, b_proj, x, x2, 512, 512);
    // ln2 -> bf16
    ln_fused_k<<<BT, 256, 0, stream>>>(x2, lnbuf);
    // h = gelu(ln2(x2) @ w_fc^T + b_fc)  (bf16)
    gemm_mfma<2><<<dim3(1024 / 128, BT / 128), 256, 0, stream>>>(
        lnbuf, wf_b, b_fc, nullptr, hbuf, 512, 1024);
    // out = x2 + h @ w_cproj^T           (f32)
    gemm_mfma<3><<<dim3(512 / 128, BT / 128), 256, 0, stream>>>(
        hbuf, wc_b, nullptr, x2, d_out, 1024, 512);
}